// Round 5
// baseline (211.230 us; speedup 1.0000x reference)
//
#include <hip/hip_runtime.h>
#include <hip/hip_bf16.h>

#define S_NODES 8192
#define P_PATHS 16
#define K_EP    16
#define D_DIM   128
#define H_DIM   64

typedef __bf16 bf16x8_t __attribute__((ext_vector_type(8)));
typedef float  f32x4_t  __attribute__((ext_vector_type(4)));

// LDS strides (elements per row), hot accesses <=2-way bank aliased (free):
#define AGGF_STRIDE  132   // floats
#define AGGBF_STRIDE 136   // bf16; rows 272B, 16B-aligned for b128 A-frag reads

// ---- prep: W1 [D][H] fp32 -> W1^T [H][D] bf16 in workspace ----
__global__ __launch_bounds__(256)
void prep_w1_kernel(const float* __restrict__ W1, __bf16* __restrict__ w1t)
{
    const int idx = blockIdx.x * 256 + threadIdx.x;   // 32 x 256 = 8192
    const int n = idx >> 7, d = idx & 127;
    w1t[idx] = (__bf16)W1[d * H_DIM + n];
}

// ---- prep: entity table fp32 -> bf16 (one streaming pass) ----
__global__ __launch_bounds__(256)
void prep_ent_kernel(const float* __restrict__ ent, __bf16* __restrict__ entbf, int n4)
{
    const int i = blockIdx.x * 256 + threadIdx.x;     // each thread: 4 elements
    if (i >= n4) return;
    float4 v = ((const float4*)ent)[i];
    union { __bf16 h[4]; uint2 u; } pk;
    pk.h[0] = (__bf16)v.x; pk.h[1] = (__bf16)v.y;
    pk.h[2] = (__bf16)v.z; pk.h[3] = (__bf16)v.w;
    ((uint2*)entbf)[i] = pk.u;
}

#define ACC8(acc, v) {                                                          \
    unsigned w0 = (v).x, w1 = (v).y, w2 = (v).z, w3 = (v).w;                    \
    acc[0] += __uint_as_float(w0 << 16); acc[1] += __uint_as_float(w0 & 0xffff0000u); \
    acc[2] += __uint_as_float(w1 << 16); acc[3] += __uint_as_float(w1 & 0xffff0000u); \
    acc[4] += __uint_as_float(w2 << 16); acc[5] += __uint_as_float(w2 & 0xffff0000u); \
    acc[6] += __uint_as_float(w3 << 16); acc[7] += __uint_as_float(w3 & 0xffff0000u); }

template<bool USE_BF16>
__global__ __launch_bounds__(256, 7)   // cap ~73 VGPR -> 7 waves/SIMD
void PathGuidedAggregator_kernel(const float*  __restrict__ ent,
                                 const __bf16* __restrict__ entbf,  // bf16 table (ws)
                                 const float*  __restrict__ b1,
                                 const float*  __restrict__ W2,
                                 const float*  __restrict__ b2,
                                 const int*    __restrict__ sids,
                                 const int*    __restrict__ eids,
                                 const void*   __restrict__ emask,
                                 const __bf16* __restrict__ w1t,    // [H][D] bf16 (ws)
                                 float*        __restrict__ out)
{
    __shared__ float  aggf [P_PATHS][AGGF_STRIDE];   // fp32 agg (epilogue w*agg)
    __shared__ __bf16 aggbf[P_PATHS][AGGBF_STRIDE];  // bf16 agg (MFMA A operand)
    __shared__ int    cnts[P_PATHS];
    __shared__ int    comp[4][4][K_EP];              // per-wave compacted endpoint ids

    const int s    = blockIdx.x;
    const int tid  = threadIdx.x;
    const int wave = tid >> 6;
    const int lane = tid & 63;

    // ---- runtime detection of bool-mask storage: int32 / uint8 / float32 ----
    const unsigned int* mw = (const unsigned int*)emask;
    unsigned int probe = mw[lane];
    const bool floatMask = (__ballot(probe == 0x3F800000u) != 0ULL);
    const bool byteMask  = !floatMask && (__ballot(probe > 1u) != 0ULL);

    // ---- one coalesced 64-lane load covers ids+mask for this wave's 4 paths ----
    const int base = (s * P_PATHS + wave * 4) * K_EP;
    const int idv  = eids[base + lane];
    int mk;
    if (floatMask)     mk = (((const float*)emask)[base + lane] != 0.0f);
    else if (byteMask) mk = ((const unsigned char*)emask)[base + lane];
    else               mk = ((const int*)emask)[base + lane];
    const unsigned long long bits_all = __ballot(mk != 0);

    const int k16  = lane & 15;
    const int pgrp = lane >> 4;
    const unsigned int bits_p = (unsigned int)((bits_all >> (16 * pgrp)) & 0xFFFFu);

    comp[wave][pgrp][k16] = 0;
    if (mk) comp[wave][pgrp][__popc(bits_p & ((1u << k16) - 1u))] = idv;
    if (lane < 4) cnts[wave * 4 + lane] = __popc((unsigned int)((bits_all >> (16 * lane)) & 0xFFFFu));

    const int carr0 = __popc((unsigned int)( bits_all        & 0xFFFFu));
    const int carr1 = __popc((unsigned int)((bits_all >> 16) & 0xFFFFu));
    const int carr2 = __popc((unsigned int)((bits_all >> 32) & 0xFFFFu));
    const int carr3 = __popc((unsigned int)((bits_all >> 48) & 0xFFFFu));

    if constexpr (USE_BF16) {
        // ---- bf16 gather: quarter-wave per row (16 lanes x 16B = 256B row) ----
        const int q   = lane >> 4;       // quarter owns slots q, q+4, q+8, q+12
        const int c16 = lane & 15;
        const uint4* __restrict__ entb = (const uint4*)entbf;
        const int cl[4] = {carr0, carr1, carr2, carr3};
        #pragma unroll
        for (int pr = 0; pr < 2; ++pr) {             // 2 paths per round
            const int pA = pr * 2, pB = pr * 2 + 1;
            const int cA = cl[pA], cB = cl[pB];
            uint4 vA[4], vB[4];
            bool  gA[4], gB[4];
            #pragma unroll
            for (int u = 0; u < 4; ++u) {
                const int slot = u * 4 + q;
                const int ida = comp[wave][pA][slot];
                const int idb = comp[wave][pB][slot];
                gA[u] = slot < cA; gB[u] = slot < cB;
                if (gA[u]) vA[u] = entb[(size_t)ida * 16 + c16];
                if (gB[u]) vB[u] = entb[(size_t)idb * 16 + c16];
            }
            float aA[8] = {0,0,0,0,0,0,0,0}, aB[8] = {0,0,0,0,0,0,0,0};
            #pragma unroll
            for (int u = 0; u < 4; ++u) {
                if (gA[u]) ACC8(aA, vA[u]);
                if (gB[u]) ACC8(aB, vB[u]);
            }
            // merge quarters (xor 16, 32)
            #pragma unroll
            for (int j = 0; j < 8; ++j) {
                aA[j] += __shfl_xor(aA[j], 16); aA[j] += __shfl_xor(aA[j], 32);
                aB[j] += __shfl_xor(aB[j], 16); aB[j] += __shfl_xor(aB[j], 32);
            }
            const float iA = 1.0f / (float)(cA > 1 ? cA : 1);
            const float iB = 1.0f / (float)(cB > 1 ? cB : 1);
            if (lane < 16) {
                #pragma unroll
                for (int j = 0; j < 8; ++j) { aA[j] *= iA; aB[j] *= iB; }
                const int ppA = wave * 4 + pA, ppB = wave * 4 + pB;
                *(float4*)&aggf[ppA][c16 * 8]     = make_float4(aA[0], aA[1], aA[2], aA[3]);
                *(float4*)&aggf[ppA][c16 * 8 + 4] = make_float4(aA[4], aA[5], aA[6], aA[7]);
                *(float4*)&aggf[ppB][c16 * 8]     = make_float4(aB[0], aB[1], aB[2], aB[3]);
                *(float4*)&aggf[ppB][c16 * 8 + 4] = make_float4(aB[4], aB[5], aB[6], aB[7]);
                union { __bf16 h[8]; uint4 u4; } pk;
                #pragma unroll
                for (int j = 0; j < 8; ++j) pk.h[j] = (__bf16)aA[j];
                *(uint4*)&aggbf[ppA][c16 * 8] = pk.u4;
                #pragma unroll
                for (int j = 0; j < 8; ++j) pk.h[j] = (__bf16)aB[j];
                *(uint4*)&aggbf[ppB][c16 * 8] = pk.u4;
            }
        }
    } else {
        // ---- fp32 gather fallback (round-4 structure) ----
        const int half = lane >> 5;
        const int col  = lane & 31;
        const float4* __restrict__ entc = (const float4*)ent + col;
        float4 acc0 = {0.f,0.f,0.f,0.f}, acc1 = acc0, acc2 = acc0, acc3 = acc0;
        #pragma unroll
        for (int u = 0; u < 8; ++u) {
            const int slot = 2 * u + half;
            const int id0 = comp[wave][0][slot];
            const int id1 = comp[wave][1][slot];
            const int id2 = comp[wave][2][slot];
            const int id3 = comp[wave][3][slot];
            if (slot < carr0) { float4 v = entc[(size_t)id0 << 5]; acc0.x += v.x; acc0.y += v.y; acc0.z += v.z; acc0.w += v.w; }
            if (slot < carr1) { float4 v = entc[(size_t)id1 << 5]; acc1.x += v.x; acc1.y += v.y; acc1.z += v.z; acc1.w += v.w; }
            if (slot < carr2) { float4 v = entc[(size_t)id2 << 5]; acc2.x += v.x; acc2.y += v.y; acc2.z += v.z; acc2.w += v.w; }
            if (slot < carr3) { float4 v = entc[(size_t)id3 << 5]; acc3.x += v.x; acc3.y += v.y; acc3.z += v.z; acc3.w += v.w; }
        }
        #pragma unroll
        for (int i = 0; i < 4; ++i) {
            float4 a = (i == 0) ? acc0 : (i == 1) ? acc1 : (i == 2) ? acc2 : acc3;
            const int cnt = (i == 0) ? carr0 : (i == 1) ? carr1 : (i == 2) ? carr2 : carr3;
            a.x += __shfl_xor(a.x, 32); a.y += __shfl_xor(a.y, 32);
            a.z += __shfl_xor(a.z, 32); a.w += __shfl_xor(a.w, 32);
            const float inv = 1.0f / (float)(cnt > 1 ? cnt : 1);
            a.x *= inv; a.y *= inv; a.z *= inv; a.w *= inv;
            if (half == 0) {
                const int p = wave * 4 + i;
                *(float4*)&aggf[p][col * 4] = a;
                union { __bf16 h[4]; uint2 u2; } pk;
                pk.h[0] = (__bf16)a.x; pk.h[1] = (__bf16)a.y;
                pk.h[2] = (__bf16)a.z; pk.h[3] = (__bf16)a.w;
                *(uint2*)&aggbf[p][col * 4] = pk.u2;
            }
        }
    }
    __syncthreads();

    if (wave != 0) return;

    // ---- MLP for all 16 paths via MFMA (wave 0) ----
    const int m    = lane & 15;
    const int quad = lane >> 4;

    bf16x8_t afr[4];
    #pragma unroll
    for (int st = 0; st < 4; ++st)
        afr[st] = *(const bf16x8_t*)&aggbf[m][st * 32 + quad * 8];

    float xp[4] = {0.f, 0.f, 0.f, 0.f};
    #pragma unroll
    for (int t = 0; t < 4; ++t) {
        const int n = t * 16 + m;
        const float b1v = b1[n];
        f32x4_t acc = {b1v, b1v, b1v, b1v};
        const __bf16* bp = w1t + n * D_DIM + quad * 8;
        #pragma unroll
        for (int st = 0; st < 4; ++st) {
            bf16x8_t bfr = *(const bf16x8_t*)(bp + st * 32);
            acc = __builtin_amdgcn_mfma_f32_16x16x32_bf16(afr[st], bfr, acc, 0, 0, 0);
        }
        const float w2v = W2[n];
        #pragma unroll
        for (int r = 0; r < 4; ++r) {
            float h = acc[r] > 0.f ? acc[r] : 0.f;
            xp[r] += h * w2v;
        }
    }
    #pragma unroll
    for (int off = 1; off < 16; off <<= 1) {
        #pragma unroll
        for (int r = 0; r < 4; ++r) xp[r] += __shfl_xor(xp[r], off);
    }

    int myc[4]; int localv = 0;
    #pragma unroll
    for (int r = 0; r < 4; ++r) { myc[r] = cnts[quad * 4 + r]; localv += (myc[r] > 0); }
    int nv = localv + __shfl_xor(localv, 16);
    nv += __shfl_xor(nv, 32);
    const float invnv = 1.0f / (float)(nv > 1 ? nv : 1);
    const float b2v = b2[0];

    float wv[4];
    #pragma unroll
    for (int r = 0; r < 4; ++r) {
        float x = xp[r] + b2v;
        float w = 1.0f / (1.0f + __expf(-x));
        wv[r] = (myc[r] > 0) ? w * invnv : 0.f;
    }

    float fx = 0.f, fy = 0.f;
    #pragma unroll
    for (int p = 0; p < P_PATHS; ++p) {
        float wp = __shfl(wv[p & 3], (p >> 2) << 4);
        float2 a = *(const float2*)&aggf[p][2 * lane];
        fx += wp * a.x; fy += wp * a.y;
    }
    const int row = sids[s];
    *(float2*)&out[(size_t)row * D_DIM + 2 * lane] = make_float2(fx, fy);
}

extern "C" void kernel_launch(void* const* d_in, const int* in_sizes, int n_in,
                              void* d_out, int out_size, void* d_ws, size_t ws_size,
                              hipStream_t stream)
{
    const float* ent  = (const float*)d_in[0];
    const float* W1   = (const float*)d_in[1];
    const float* b1   = (const float*)d_in[2];
    const float* W2   = (const float*)d_in[3];
    const float* b2   = (const float*)d_in[4];
    const int*   sids = (const int*)d_in[5];
    const int*   eids = (const int*)d_in[6];
    const void*  emsk = (const void*)d_in[7];
    float* out = (float*)d_out;

    const int ND = in_sizes[0];                       // N*D elements of entity table
    __bf16* w1t_ws = (__bf16*)d_ws;                   // 16 KB
    __bf16* entbf  = (__bf16*)((char*)d_ws + 16384);  // 2*ND bytes
    const bool useBf16 = (ws_size >= 16384 + (size_t)ND * 2) && ((ND & 3) == 0);

    hipMemsetAsync(d_out, 0, (size_t)out_size * sizeof(float), stream);
    prep_w1_kernel<<<32, 256, 0, stream>>>(W1, w1t_ws);
    if (useBf16) {
        const int n4 = ND >> 2;
        prep_ent_kernel<<<(n4 + 255) / 256, 256, 0, stream>>>(ent, entbf, n4);
        PathGuidedAggregator_kernel<true><<<S_NODES, 256, 0, stream>>>(
            ent, (const __bf16*)entbf, b1, W2, b2, sids, eids, emsk, (const __bf16*)w1t_ws, out);
    } else {
        PathGuidedAggregator_kernel<false><<<S_NODES, 256, 0, stream>>>(
            ent, (const __bf16*)entbf, b1, W2, b2, sids, eids, emsk, (const __bf16*)w1t_ws, out);
    }
}

// Round 6
// 177.767 us; speedup vs baseline: 1.1882x; 1.1882x over previous
//
#include <hip/hip_runtime.h>
#include <hip/hip_bf16.h>

#define S_NODES 8192
#define P_PATHS 16
#define K_EP    16
#define D_DIM   128
#define H_DIM   64

typedef __bf16 bf16x8_t __attribute__((ext_vector_type(8)));
typedef float  f32x4_t  __attribute__((ext_vector_type(4)));

// LDS strides (elements per row), hot accesses <=2-way bank aliased (free):
#define AGGF_STRIDE  132   // floats
#define AGGBF_STRIDE 136   // bf16; rows 272B, 16B-aligned for b128 A-frag reads

// ---- prep: W1 [D][H] fp32 -> W1^T [H][D] bf16 in workspace ----
__global__ __launch_bounds__(256)
void prep_w1_kernel(const float* __restrict__ W1, __bf16* __restrict__ w1t)
{
    const int idx = blockIdx.x * 256 + threadIdx.x;   // 32 x 256 = 8192
    const int n = idx >> 7, d = idx & 127;
    w1t[idx] = (__bf16)W1[d * H_DIM + n];
}

// ---- prep: entity table fp32 -> bf16 (one streaming pass) ----
__global__ __launch_bounds__(256)
void prep_ent_kernel(const float* __restrict__ ent, __bf16* __restrict__ entbf, int n4)
{
    const int i = blockIdx.x * 256 + threadIdx.x;     // each thread: 4 elements
    if (i >= n4) return;
    float4 v = ((const float4*)ent)[i];
    union { __bf16 h[4]; uint2 u; } pk;
    pk.h[0] = (__bf16)v.x; pk.h[1] = (__bf16)v.y;
    pk.h[2] = (__bf16)v.z; pk.h[3] = (__bf16)v.w;
    ((uint2*)entbf)[i] = pk.u;
}

// unpack a 16B bf16x8 chunk into two fp32 float4 accumulators
__device__ __forceinline__ void acc_row(float4& lo, float4& hi, uint4 r)
{
    lo.x += __uint_as_float(r.x << 16); lo.y += __uint_as_float(r.x & 0xffff0000u);
    lo.z += __uint_as_float(r.y << 16); lo.w += __uint_as_float(r.y & 0xffff0000u);
    hi.x += __uint_as_float(r.z << 16); hi.y += __uint_as_float(r.z & 0xffff0000u);
    hi.z += __uint_as_float(r.w << 16); hi.w += __uint_as_float(r.w & 0xffff0000u);
}

__device__ __forceinline__ void merge_xor(float4& v)
{
    v.x += __shfl_xor(v.x, 16); v.y += __shfl_xor(v.y, 16);
    v.z += __shfl_xor(v.z, 16); v.w += __shfl_xor(v.w, 16);
    v.x += __shfl_xor(v.x, 32); v.y += __shfl_xor(v.y, 32);
    v.z += __shfl_xor(v.z, 32); v.w += __shfl_xor(v.w, 32);
}

template<bool USE_BF16>
__global__ __launch_bounds__(256, 6)   // cap ~85 VGPR -> 6 waves/SIMD (75% occ), room for in-flight batch
void PathGuidedAggregator_kernel(const float*  __restrict__ ent,
                                 const __bf16* __restrict__ entbf,  // bf16 table (ws)
                                 const float*  __restrict__ b1,
                                 const float*  __restrict__ W2,
                                 const float*  __restrict__ b2,
                                 const int*    __restrict__ sids,
                                 const int*    __restrict__ eids,
                                 const void*   __restrict__ emask,
                                 const __bf16* __restrict__ w1t,    // [H][D] bf16 (ws)
                                 float*        __restrict__ out)
{
    __shared__ float  aggf [P_PATHS][AGGF_STRIDE];   // fp32 agg (epilogue w*agg)
    __shared__ __bf16 aggbf[P_PATHS][AGGBF_STRIDE];  // bf16 agg (MFMA A operand)
    __shared__ int    cnts[P_PATHS];
    __shared__ int    comp[4][4][K_EP];              // per-wave compacted endpoint ids

    const int s    = blockIdx.x;
    const int tid  = threadIdx.x;
    const int wave = tid >> 6;
    const int lane = tid & 63;

    // ---- runtime detection of bool-mask storage: int32 / uint8 / float32 ----
    const unsigned int* mw = (const unsigned int*)emask;
    unsigned int probe = mw[lane];
    const bool floatMask = (__ballot(probe == 0x3F800000u) != 0ULL);
    const bool byteMask  = !floatMask && (__ballot(probe > 1u) != 0ULL);

    // ---- one coalesced 64-lane load covers ids+mask for this wave's 4 paths ----
    const int base = (s * P_PATHS + wave * 4) * K_EP;
    const int idv  = eids[base + lane];
    int mk;
    if (floatMask)     mk = (((const float*)emask)[base + lane] != 0.0f);
    else if (byteMask) mk = ((const unsigned char*)emask)[base + lane];
    else               mk = ((const int*)emask)[base + lane];
    const unsigned long long bits_all = __ballot(mk != 0);

    const int k16  = lane & 15;
    const int pgrp = lane >> 4;
    const unsigned int bits_p = (unsigned int)((bits_all >> (16 * pgrp)) & 0xFFFFu);

    comp[wave][pgrp][k16] = 0;   // slots >= cnt stay 0 -> safe row
    if (mk) comp[wave][pgrp][__popc(bits_p & ((1u << k16) - 1u))] = idv;
    if (lane < 4) cnts[wave * 4 + lane] = __popc((unsigned int)((bits_all >> (16 * lane)) & 0xFFFFu));

    const int c0 = __popc((unsigned int)( bits_all        & 0xFFFFu));
    const int c1 = __popc((unsigned int)((bits_all >> 16) & 0xFFFFu));
    const int c2 = __popc((unsigned int)((bits_all >> 32) & 0xFFFFu));
    const int c3 = __popc((unsigned int)((bits_all >> 48) & 0xFFFFu));

    const int q   = lane >> 4;       // quarter: owns slots q, q+4, q+8, q+12
    const int c16 = lane & 15;

    if constexpr (USE_BF16) {
        // ---- bf16 gather: quarter-wave per row (16 lanes x 16B = 256B row), 4 paths in parallel.
        // NO per-thread arrays anywhere -> nothing can go to scratch.
        const uint4* __restrict__ entb = (const uint4*)entbf + c16;
        float4 l0 = {0,0,0,0}, h0 = l0, l1 = l0, h1 = l0, l2 = l0, h2 = l0, l3 = l0, h3 = l0;
        #pragma unroll
        for (int u = 0; u < 4; ++u) {
            const int slot = q + 4 * u;
            const bool g0 = slot < c0, g1 = slot < c1, g2 = slot < c2, g3 = slot < c3;
            uint4 r0, r1, r2, r3;
            if (g0) r0 = entb[(size_t)comp[wave][0][slot] * 16];
            if (g1) r1 = entb[(size_t)comp[wave][1][slot] * 16];
            if (g2) r2 = entb[(size_t)comp[wave][2][slot] * 16];
            if (g3) r3 = entb[(size_t)comp[wave][3][slot] * 16];
            if (g0) acc_row(l0, h0, r0);
            if (g1) acc_row(l1, h1, r1);
            if (g2) acc_row(l2, h2, r2);
            if (g3) acc_row(l3, h3, r3);
        }
        // merge the 4 quarters (xor 16 then 32) -> every lane holds full sums
        merge_xor(l0); merge_xor(h0); merge_xor(l1); merge_xor(h1);
        merge_xor(l2); merge_xor(h2); merge_xor(l3); merge_xor(h3);

        // quarter q stores path q (all 64 lanes active)
        const int   cq   = (q == 0) ? c0 : (q == 1) ? c1 : (q == 2) ? c2 : c3;
        const float invq = 1.0f / (float)(cq > 1 ? cq : 1);
        float4 lo = (q == 0) ? l0 : (q == 1) ? l1 : (q == 2) ? l2 : l3;
        float4 hi = (q == 0) ? h0 : (q == 1) ? h1 : (q == 2) ? h2 : h3;
        lo.x *= invq; lo.y *= invq; lo.z *= invq; lo.w *= invq;
        hi.x *= invq; hi.y *= invq; hi.z *= invq; hi.w *= invq;
        const int pw = wave * 4 + q;
        *(float4*)&aggf[pw][c16 * 8]     = lo;
        *(float4*)&aggf[pw][c16 * 8 + 4] = hi;
        union { __bf16 h[8]; uint4 u4; } pk;
        pk.h[0] = (__bf16)lo.x; pk.h[1] = (__bf16)lo.y; pk.h[2] = (__bf16)lo.z; pk.h[3] = (__bf16)lo.w;
        pk.h[4] = (__bf16)hi.x; pk.h[5] = (__bf16)hi.y; pk.h[6] = (__bf16)hi.z; pk.h[7] = (__bf16)hi.w;
        *(uint4*)&aggbf[pw][c16 * 8] = pk.u4;
    } else {
        // ---- fp32 fallback (round-4 structure, known spill-free) ----
        const int half = lane >> 5;
        const int col  = lane & 31;
        const float4* __restrict__ entc = (const float4*)ent + col;
        float4 acc0 = {0.f,0.f,0.f,0.f}, acc1 = acc0, acc2 = acc0, acc3 = acc0;
        #pragma unroll
        for (int u = 0; u < 8; ++u) {
            const int slot = 2 * u + half;
            const int id0 = comp[wave][0][slot];
            const int id1 = comp[wave][1][slot];
            const int id2 = comp[wave][2][slot];
            const int id3 = comp[wave][3][slot];
            if (slot < c0) { float4 v = entc[(size_t)id0 << 5]; acc0.x += v.x; acc0.y += v.y; acc0.z += v.z; acc0.w += v.w; }
            if (slot < c1) { float4 v = entc[(size_t)id1 << 5]; acc1.x += v.x; acc1.y += v.y; acc1.z += v.z; acc1.w += v.w; }
            if (slot < c2) { float4 v = entc[(size_t)id2 << 5]; acc2.x += v.x; acc2.y += v.y; acc2.z += v.z; acc2.w += v.w; }
            if (slot < c3) { float4 v = entc[(size_t)id3 << 5]; acc3.x += v.x; acc3.y += v.y; acc3.z += v.z; acc3.w += v.w; }
        }
        #pragma unroll
        for (int i = 0; i < 4; ++i) {
            float4 a = (i == 0) ? acc0 : (i == 1) ? acc1 : (i == 2) ? acc2 : acc3;
            const int cnt = (i == 0) ? c0 : (i == 1) ? c1 : (i == 2) ? c2 : c3;
            a.x += __shfl_xor(a.x, 32); a.y += __shfl_xor(a.y, 32);
            a.z += __shfl_xor(a.z, 32); a.w += __shfl_xor(a.w, 32);
            const float inv = 1.0f / (float)(cnt > 1 ? cnt : 1);
            a.x *= inv; a.y *= inv; a.z *= inv; a.w *= inv;
            if (half == 0) {
                const int p = wave * 4 + i;
                *(float4*)&aggf[p][col * 4] = a;
                union { __bf16 h[4]; uint2 u2; } pk;
                pk.h[0] = (__bf16)a.x; pk.h[1] = (__bf16)a.y;
                pk.h[2] = (__bf16)a.z; pk.h[3] = (__bf16)a.w;
                *(uint2*)&aggbf[p][col * 4] = pk.u2;
            }
        }
    }
    __syncthreads();

    if (wave != 0) return;

    // ---- MLP for all 16 paths via MFMA (wave 0) ----
    const int m    = lane & 15;
    const int quad = lane >> 4;

    bf16x8_t afr[4];
    #pragma unroll
    for (int st = 0; st < 4; ++st)
        afr[st] = *(const bf16x8_t*)&aggbf[m][st * 32 + quad * 8];

    float xp[4] = {0.f, 0.f, 0.f, 0.f};
    #pragma unroll
    for (int t = 0; t < 4; ++t) {
        const int n = t * 16 + m;
        const float b1v = b1[n];
        f32x4_t acc = {b1v, b1v, b1v, b1v};
        const __bf16* bp = w1t + n * D_DIM + quad * 8;
        #pragma unroll
        for (int st = 0; st < 4; ++st) {
            bf16x8_t bfr = *(const bf16x8_t*)(bp + st * 32);
            acc = __builtin_amdgcn_mfma_f32_16x16x32_bf16(afr[st], bfr, acc, 0, 0, 0);
        }
        const float w2v = W2[n];
        #pragma unroll
        for (int r = 0; r < 4; ++r) {
            float h = acc[r] > 0.f ? acc[r] : 0.f;
            xp[r] += h * w2v;
        }
    }
    #pragma unroll
    for (int off = 1; off < 16; off <<= 1) {
        #pragma unroll
        for (int r = 0; r < 4; ++r) xp[r] += __shfl_xor(xp[r], off);
    }

    int myc[4]; int localv = 0;
    #pragma unroll
    for (int r = 0; r < 4; ++r) { myc[r] = cnts[quad * 4 + r]; localv += (myc[r] > 0); }
    int nv = localv + __shfl_xor(localv, 16);
    nv += __shfl_xor(nv, 32);
    const float invnv = 1.0f / (float)(nv > 1 ? nv : 1);
    const float b2v = b2[0];

    float wv[4];
    #pragma unroll
    for (int r = 0; r < 4; ++r) {
        float x = xp[r] + b2v;
        float w = 1.0f / (1.0f + __expf(-x));
        wv[r] = (myc[r] > 0) ? w * invnv : 0.f;
    }

    float fx = 0.f, fy = 0.f;
    #pragma unroll
    for (int p = 0; p < P_PATHS; ++p) {
        float wp = __shfl(wv[p & 3], (p >> 2) << 4);
        float2 a = *(const float2*)&aggf[p][2 * lane];
        fx += wp * a.x; fy += wp * a.y;
    }
    const int row = sids[s];
    *(float2*)&out[(size_t)row * D_DIM + 2 * lane] = make_float2(fx, fy);
}

extern "C" void kernel_launch(void* const* d_in, const int* in_sizes, int n_in,
                              void* d_out, int out_size, void* d_ws, size_t ws_size,
                              hipStream_t stream)
{
    const float* ent  = (const float*)d_in[0];
    const float* W1   = (const float*)d_in[1];
    const float* b1   = (const float*)d_in[2];
    const float* W2   = (const float*)d_in[3];
    const float* b2   = (const float*)d_in[4];
    const int*   sids = (const int*)d_in[5];
    const int*   eids = (const int*)d_in[6];
    const void*  emsk = (const void*)d_in[7];
    float* out = (float*)d_out;

    const int ND = in_sizes[0];                       // N*D elements of entity table
    __bf16* w1t_ws = (__bf16*)d_ws;                   // 16 KB
    __bf16* entbf  = (__bf16*)((char*)d_ws + 16384);  // 2*ND bytes
    const bool useBf16 = (ws_size >= 16384 + (size_t)ND * 2) && ((ND & 3) == 0);

    hipMemsetAsync(d_out, 0, (size_t)out_size * sizeof(float), stream);
    prep_w1_kernel<<<32, 256, 0, stream>>>(W1, w1t_ws);
    if (useBf16) {
        const int n4 = ND >> 2;
        prep_ent_kernel<<<(n4 + 255) / 256, 256, 0, stream>>>(ent, entbf, n4);
        PathGuidedAggregator_kernel<true><<<S_NODES, 256, 0, stream>>>(
            ent, (const __bf16*)entbf, b1, W2, b2, sids, eids, emsk, (const __bf16*)w1t_ws, out);
    } else {
        PathGuidedAggregator_kernel<false><<<S_NODES, 256, 0, stream>>>(
            ent, (const __bf16*)entbf, b1, W2, b2, sids, eids, emsk, (const __bf16*)w1t_ws, out);
    }
}

// Round 7
// 175.053 us; speedup vs baseline: 1.2067x; 1.0155x over previous
//
#include <hip/hip_runtime.h>
#include <hip/hip_bf16.h>

#define S_NODES 8192
#define P_PATHS 16
#define K_EP    16
#define D_DIM   128
#define H_DIM   64

typedef __bf16 bf16x8_t __attribute__((ext_vector_type(8)));
typedef float  f32x4_t  __attribute__((ext_vector_type(4)));

// LDS strides (elements per row), hot accesses <=2-way bank aliased (free):
#define AGGF_STRIDE  132   // floats
#define AGGBF_STRIDE 136   // bf16; rows 272B, 16B-aligned for b128 A-frag reads

// ---- fused prep: out=0, entity fp32->bf16, W1 -> W1^T bf16 (one dispatch) ----
__global__ __launch_bounds__(256)
void prep_fused_kernel(const float* __restrict__ ent, const float* __restrict__ W1,
                       __bf16* __restrict__ entbf, __bf16* __restrict__ w1t,
                       float4* __restrict__ out4, int n4, int o4)
{
    const int i = blockIdx.x * 256 + threadIdx.x;
    if (i < n4) {
        float4 v = ((const float4*)ent)[i];
        union { __bf16 h[4]; uint2 u; } pk;
        pk.h[0] = (__bf16)v.x; pk.h[1] = (__bf16)v.y;
        pk.h[2] = (__bf16)v.z; pk.h[3] = (__bf16)v.w;
        ((uint2*)entbf)[i] = pk.u;
    }
    if (i < o4) out4[i] = make_float4(0.f, 0.f, 0.f, 0.f);
    if (i < D_DIM * H_DIM) {
        const int n = i >> 7, d = i & 127;
        w1t[i] = (__bf16)W1[d * H_DIM + n];
    }
}

// ---- fallback-path preps ----
__global__ __launch_bounds__(256)
void prep_w1_kernel(const float* __restrict__ W1, __bf16* __restrict__ w1t)
{
    const int idx = blockIdx.x * 256 + threadIdx.x;   // 32 x 256 = 8192
    const int n = idx >> 7, d = idx & 127;
    w1t[idx] = (__bf16)W1[d * H_DIM + n];
}

// unpack a 16B bf16x8 chunk into two fp32 float4 accumulators
__device__ __forceinline__ void acc_row(float4& lo, float4& hi, uint4 r)
{
    lo.x += __uint_as_float(r.x << 16); lo.y += __uint_as_float(r.x & 0xffff0000u);
    lo.z += __uint_as_float(r.y << 16); lo.w += __uint_as_float(r.y & 0xffff0000u);
    hi.x += __uint_as_float(r.z << 16); hi.y += __uint_as_float(r.z & 0xffff0000u);
    hi.z += __uint_as_float(r.w << 16); hi.w += __uint_as_float(r.w & 0xffff0000u);
}

__device__ __forceinline__ void merge_xor(float4& v)
{
    v.x += __shfl_xor(v.x, 16); v.y += __shfl_xor(v.y, 16);
    v.z += __shfl_xor(v.z, 16); v.w += __shfl_xor(v.w, 16);
    v.x += __shfl_xor(v.x, 32); v.y += __shfl_xor(v.y, 32);
    v.z += __shfl_xor(v.z, 32); v.w += __shfl_xor(v.w, 32);
}

template<bool USE_BF16>
__global__ __launch_bounds__(256, 8)   // VGPR<=64 (uses ~32), LDS 14.3KB -> 8 blocks/CU (100% cap)
void PathGuidedAggregator_kernel(const float*  __restrict__ ent,
                                 const __bf16* __restrict__ entbf,  // bf16 table (ws)
                                 const float*  __restrict__ b1,
                                 const float*  __restrict__ W2,
                                 const float*  __restrict__ b2,
                                 const int*    __restrict__ sids,
                                 const int*    __restrict__ eids,
                                 const void*   __restrict__ emask,
                                 const __bf16* __restrict__ w1t,    // [H][D] bf16 (ws)
                                 float*        __restrict__ out)
{
    __shared__ float  aggf [P_PATHS][AGGF_STRIDE];   // fp32 agg (epilogue w*agg)
    __shared__ __bf16 aggbf[P_PATHS][AGGBF_STRIDE];  // bf16 agg (MFMA A operand)
    __shared__ int    cnts[P_PATHS];
    __shared__ int    comp[4][4][K_EP];              // per-wave compacted endpoint ids

    const int s    = blockIdx.x;
    const int tid  = threadIdx.x;
    const int wave = tid >> 6;
    const int lane = tid & 63;

    // ---- runtime detection of bool-mask storage: int32 / uint8 / float32 ----
    const unsigned int* mw = (const unsigned int*)emask;
    unsigned int probe = mw[lane];
    const bool floatMask = (__ballot(probe == 0x3F800000u) != 0ULL);
    const bool byteMask  = !floatMask && (__ballot(probe > 1u) != 0ULL);

    // ---- one coalesced 64-lane load covers ids+mask for this wave's 4 paths ----
    const int base = (s * P_PATHS + wave * 4) * K_EP;
    const int idv  = eids[base + lane];
    int mk;
    if (floatMask)     mk = (((const float*)emask)[base + lane] != 0.0f);
    else if (byteMask) mk = ((const unsigned char*)emask)[base + lane];
    else               mk = ((const int*)emask)[base + lane];
    const unsigned long long bits_all = __ballot(mk != 0);

    const int k16  = lane & 15;
    const int pgrp = lane >> 4;
    const unsigned int bits_p = (unsigned int)((bits_all >> (16 * pgrp)) & 0xFFFFu);

    comp[wave][pgrp][k16] = 0;   // slots >= cnt stay 0 -> safe row
    if (mk) comp[wave][pgrp][__popc(bits_p & ((1u << k16) - 1u))] = idv;
    if (lane < 4) cnts[wave * 4 + lane] = __popc((unsigned int)((bits_all >> (16 * lane)) & 0xFFFFu));

    const int c0 = __popc((unsigned int)( bits_all        & 0xFFFFu));
    const int c1 = __popc((unsigned int)((bits_all >> 16) & 0xFFFFu));
    const int c2 = __popc((unsigned int)((bits_all >> 32) & 0xFFFFu));
    const int c3 = __popc((unsigned int)((bits_all >> 48) & 0xFFFFu));

    const int q   = lane >> 4;       // quarter: owns slots q, q+4, q+8, q+12
    const int c16 = lane & 15;

    if constexpr (USE_BF16) {
        // ---- bf16 gather: quarter-wave per row (16 lanes x 16B = 256B row), 4 paths in parallel.
        // No per-thread arrays -> spill-proof (WRITE_SIZE is the alarm).
        const uint4* __restrict__ entb = (const uint4*)entbf + c16;
        float4 l0 = {0,0,0,0}, h0 = l0, l1 = l0, h1 = l0, l2 = l0, h2 = l0, l3 = l0, h3 = l0;
        #pragma unroll
        for (int u = 0; u < 4; ++u) {
            const int slot = q + 4 * u;
            const bool g0 = slot < c0, g1 = slot < c1, g2 = slot < c2, g3 = slot < c3;
            uint4 r0, r1, r2, r3;
            if (g0) r0 = entb[(size_t)comp[wave][0][slot] * 16];
            if (g1) r1 = entb[(size_t)comp[wave][1][slot] * 16];
            if (g2) r2 = entb[(size_t)comp[wave][2][slot] * 16];
            if (g3) r3 = entb[(size_t)comp[wave][3][slot] * 16];
            if (g0) acc_row(l0, h0, r0);
            if (g1) acc_row(l1, h1, r1);
            if (g2) acc_row(l2, h2, r2);
            if (g3) acc_row(l3, h3, r3);
        }
        // merge the 4 quarters (xor 16 then 32) -> every lane holds full sums
        merge_xor(l0); merge_xor(h0); merge_xor(l1); merge_xor(h1);
        merge_xor(l2); merge_xor(h2); merge_xor(l3); merge_xor(h3);

        // quarter q stores path q (all 64 lanes active)
        const int   cq   = (q == 0) ? c0 : (q == 1) ? c1 : (q == 2) ? c2 : c3;
        const float invq = 1.0f / (float)(cq > 1 ? cq : 1);
        float4 lo = (q == 0) ? l0 : (q == 1) ? l1 : (q == 2) ? l2 : l3;
        float4 hi = (q == 0) ? h0 : (q == 1) ? h1 : (q == 2) ? h2 : h3;
        lo.x *= invq; lo.y *= invq; lo.z *= invq; lo.w *= invq;
        hi.x *= invq; hi.y *= invq; hi.z *= invq; hi.w *= invq;
        const int pw = wave * 4 + q;
        *(float4*)&aggf[pw][c16 * 8]     = lo;
        *(float4*)&aggf[pw][c16 * 8 + 4] = hi;
        union { __bf16 h[8]; uint4 u4; } pk;
        pk.h[0] = (__bf16)lo.x; pk.h[1] = (__bf16)lo.y; pk.h[2] = (__bf16)lo.z; pk.h[3] = (__bf16)lo.w;
        pk.h[4] = (__bf16)hi.x; pk.h[5] = (__bf16)hi.y; pk.h[6] = (__bf16)hi.z; pk.h[7] = (__bf16)hi.w;
        *(uint4*)&aggbf[pw][c16 * 8] = pk.u4;
    } else {
        // ---- fp32 fallback (round-4 structure, known spill-free) ----
        const int half = lane >> 5;
        const int col  = lane & 31;
        const float4* __restrict__ entc = (const float4*)ent + col;
        float4 acc0 = {0.f,0.f,0.f,0.f}, acc1 = acc0, acc2 = acc0, acc3 = acc0;
        #pragma unroll
        for (int u = 0; u < 8; ++u) {
            const int slot = 2 * u + half;
            const int id0 = comp[wave][0][slot];
            const int id1 = comp[wave][1][slot];
            const int id2 = comp[wave][2][slot];
            const int id3 = comp[wave][3][slot];
            if (slot < c0) { float4 v = entc[(size_t)id0 << 5]; acc0.x += v.x; acc0.y += v.y; acc0.z += v.z; acc0.w += v.w; }
            if (slot < c1) { float4 v = entc[(size_t)id1 << 5]; acc1.x += v.x; acc1.y += v.y; acc1.z += v.z; acc1.w += v.w; }
            if (slot < c2) { float4 v = entc[(size_t)id2 << 5]; acc2.x += v.x; acc2.y += v.y; acc2.z += v.z; acc2.w += v.w; }
            if (slot < c3) { float4 v = entc[(size_t)id3 << 5]; acc3.x += v.x; acc3.y += v.y; acc3.z += v.z; acc3.w += v.w; }
        }
        #pragma unroll
        for (int i = 0; i < 4; ++i) {
            float4 a = (i == 0) ? acc0 : (i == 1) ? acc1 : (i == 2) ? acc2 : acc3;
            const int cnt = (i == 0) ? c0 : (i == 1) ? c1 : (i == 2) ? c2 : c3;
            a.x += __shfl_xor(a.x, 32); a.y += __shfl_xor(a.y, 32);
            a.z += __shfl_xor(a.z, 32); a.w += __shfl_xor(a.w, 32);
            const float inv = 1.0f / (float)(cnt > 1 ? cnt : 1);
            a.x *= inv; a.y *= inv; a.z *= inv; a.w *= inv;
            if (half == 0) {
                const int p = wave * 4 + i;
                *(float4*)&aggf[p][col * 4] = a;
                union { __bf16 h[4]; uint2 u2; } pk;
                pk.h[0] = (__bf16)a.x; pk.h[1] = (__bf16)a.y;
                pk.h[2] = (__bf16)a.z; pk.h[3] = (__bf16)a.w;
                *(uint2*)&aggbf[p][col * 4] = pk.u2;
            }
        }
    }
    __syncthreads();

    if (wave != 0) return;

    // ---- MLP for all 16 paths via MFMA (wave 0) ----
    const int m    = lane & 15;
    const int quad = lane >> 4;

    bf16x8_t afr[4];
    #pragma unroll
    for (int st = 0; st < 4; ++st)
        afr[st] = *(const bf16x8_t*)&aggbf[m][st * 32 + quad * 8];

    float xp[4] = {0.f, 0.f, 0.f, 0.f};
    #pragma unroll
    for (int t = 0; t < 4; ++t) {
        const int n = t * 16 + m;
        const float b1v = b1[n];
        f32x4_t acc = {b1v, b1v, b1v, b1v};
        const __bf16* bp = w1t + n * D_DIM + quad * 8;
        #pragma unroll
        for (int st = 0; st < 4; ++st) {
            bf16x8_t bfr = *(const bf16x8_t*)(bp + st * 32);
            acc = __builtin_amdgcn_mfma_f32_16x16x32_bf16(afr[st], bfr, acc, 0, 0, 0);
        }
        const float w2v = W2[n];
        #pragma unroll
        for (int r = 0; r < 4; ++r) {
            float h = acc[r] > 0.f ? acc[r] : 0.f;
            xp[r] += h * w2v;
        }
    }
    #pragma unroll
    for (int off = 1; off < 16; off <<= 1) {
        #pragma unroll
        for (int r = 0; r < 4; ++r) xp[r] += __shfl_xor(xp[r], off);
    }

    int myc[4]; int localv = 0;
    #pragma unroll
    for (int r = 0; r < 4; ++r) { myc[r] = cnts[quad * 4 + r]; localv += (myc[r] > 0); }
    int nv = localv + __shfl_xor(localv, 16);
    nv += __shfl_xor(nv, 32);
    const float invnv = 1.0f / (float)(nv > 1 ? nv : 1);
    const float b2v = b2[0];

    float wv[4];
    #pragma unroll
    for (int r = 0; r < 4; ++r) {
        float x = xp[r] + b2v;
        float w = 1.0f / (1.0f + __expf(-x));
        wv[r] = (myc[r] > 0) ? w * invnv : 0.f;
    }

    float fx = 0.f, fy = 0.f;
    #pragma unroll
    for (int p = 0; p < P_PATHS; ++p) {
        float wp = __shfl(wv[p & 3], (p >> 2) << 4);
        float2 a = *(const float2*)&aggf[p][2 * lane];
        fx += wp * a.x; fy += wp * a.y;
    }
    const int row = sids[s];
    *(float2*)&out[(size_t)row * D_DIM + 2 * lane] = make_float2(fx, fy);
}

extern "C" void kernel_launch(void* const* d_in, const int* in_sizes, int n_in,
                              void* d_out, int out_size, void* d_ws, size_t ws_size,
                              hipStream_t stream)
{
    const float* ent  = (const float*)d_in[0];
    const float* W1   = (const float*)d_in[1];
    const float* b1   = (const float*)d_in[2];
    const float* W2   = (const float*)d_in[3];
    const float* b2   = (const float*)d_in[4];
    const int*   sids = (const int*)d_in[5];
    const int*   eids = (const int*)d_in[6];
    const void*  emsk = (const void*)d_in[7];
    float* out = (float*)d_out;

    const int ND = in_sizes[0];                       // N*D elements of entity table
    __bf16* w1t_ws = (__bf16*)d_ws;                   // 16 KB
    __bf16* entbf  = (__bf16*)((char*)d_ws + 16384);  // 2*ND bytes
    const bool useBf16 = (ws_size >= 16384 + (size_t)ND * 2) && ((ND & 3) == 0) && ((out_size & 3) == 0);

    if (useBf16) {
        const int n4 = ND >> 2, o4 = out_size >> 2;
        const int mx = n4 > o4 ? n4 : o4;
        prep_fused_kernel<<<(mx + 255) / 256, 256, 0, stream>>>(ent, W1, entbf, w1t_ws,
                                                                (float4*)out, n4, o4);
        PathGuidedAggregator_kernel<true><<<S_NODES, 256, 0, stream>>>(
            ent, (const __bf16*)entbf, b1, W2, b2, sids, eids, emsk, (const __bf16*)w1t_ws, out);
    } else {
        hipMemsetAsync(d_out, 0, (size_t)out_size * sizeof(float), stream);
        prep_w1_kernel<<<32, 256, 0, stream>>>(W1, w1t_ws);
        PathGuidedAggregator_kernel<false><<<S_NODES, 256, 0, stream>>>(
            ent, (const __bf16*)entbf, b1, W2, b2, sids, eids, emsk, (const __bf16*)w1t_ws, out);
    }
}

// Round 8
// 169.018 us; speedup vs baseline: 1.2498x; 1.0357x over previous
//
#include <hip/hip_runtime.h>
#include <hip/hip_bf16.h>

#define S_NODES 8192
#define P_PATHS 16
#define K_EP    16
#define D_DIM   128
#define H_DIM   64

typedef __bf16 bf16x8_t __attribute__((ext_vector_type(8)));
typedef float  f32x4_t  __attribute__((ext_vector_type(4)));

// LDS strides (elements per row), hot accesses <=2-way bank aliased (free):
#define AGGF_STRIDE  132   // floats
#define AGGBF_STRIDE 136   // bf16; rows 272B, 16B-aligned for b128 A-frag reads

// ---- fused prep: out=0, entity fp32->bf16 (+1 zero pad row), W1 -> W1^T bf16 ----
__global__ __launch_bounds__(256)
void prep_fused_kernel(const float* __restrict__ ent, const float* __restrict__ W1,
                       __bf16* __restrict__ entbf, __bf16* __restrict__ w1t,
                       float4* __restrict__ out4, int n4, int o4)
{
    const int i = blockIdx.x * 256 + threadIdx.x;
    if (i < n4) {
        float4 v = ((const float4*)ent)[i];
        union { __bf16 h[4]; uint2 u; } pk;
        pk.h[0] = (__bf16)v.x; pk.h[1] = (__bf16)v.y;
        pk.h[2] = (__bf16)v.z; pk.h[3] = (__bf16)v.w;
        ((uint2*)entbf)[i] = pk.u;
    }
    if (i < 32)  // zero pad row at entity index N (256 B)
        ((uint2*)entbf)[n4 + i] = make_uint2(0u, 0u);
    if (i < o4) out4[i] = make_float4(0.f, 0.f, 0.f, 0.f);
    if (i < D_DIM * H_DIM) {
        const int n = i >> 7, d = i & 127;
        w1t[i] = (__bf16)W1[d * H_DIM + n];
    }
}

// ---- fallback-path prep ----
__global__ __launch_bounds__(256)
void prep_w1_kernel(const float* __restrict__ W1, __bf16* __restrict__ w1t)
{
    const int idx = blockIdx.x * 256 + threadIdx.x;   // 32 x 256 = 8192
    const int n = idx >> 7, d = idx & 127;
    w1t[idx] = (__bf16)W1[d * H_DIM + n];
}

// unpack a 16B bf16x8 chunk into two fp32 float4 accumulators
__device__ __forceinline__ void acc_row(float4& lo, float4& hi, uint4 r)
{
    lo.x += __uint_as_float(r.x << 16); lo.y += __uint_as_float(r.x & 0xffff0000u);
    lo.z += __uint_as_float(r.y << 16); lo.w += __uint_as_float(r.y & 0xffff0000u);
    hi.x += __uint_as_float(r.z << 16); hi.y += __uint_as_float(r.z & 0xffff0000u);
    hi.z += __uint_as_float(r.w << 16); hi.w += __uint_as_float(r.w & 0xffff0000u);
}

__device__ __forceinline__ void merge_xor(float4& v)
{
    v.x += __shfl_xor(v.x, 16); v.y += __shfl_xor(v.y, 16);
    v.z += __shfl_xor(v.z, 16); v.w += __shfl_xor(v.w, 16);
    v.x += __shfl_xor(v.x, 32); v.y += __shfl_xor(v.y, 32);
    v.z += __shfl_xor(v.z, 32); v.w += __shfl_xor(v.w, 32);
}

template<bool USE_BF16>
__global__ __launch_bounds__(256, 5)   // <=102 VGPR: room for 8-deep in-flight load pipeline
void PathGuidedAggregator_kernel(const float*  __restrict__ ent,
                                 const __bf16* __restrict__ entbf,  // bf16 table + zero pad row (ws)
                                 const float*  __restrict__ b1,
                                 const float*  __restrict__ W2,
                                 const float*  __restrict__ b2,
                                 const int*    __restrict__ sids,
                                 const int*    __restrict__ eids,
                                 const void*   __restrict__ emask,
                                 const __bf16* __restrict__ w1t,    // [H][D] bf16 (ws)
                                 float*        __restrict__ out,
                                 int nent)                          // pad row index
{
    __shared__ float  aggf [P_PATHS][AGGF_STRIDE];   // fp32 agg (epilogue w*agg)
    __shared__ __bf16 aggbf[P_PATHS][AGGBF_STRIDE];  // bf16 agg (MFMA A operand)
    __shared__ int    cnts[P_PATHS];
    __shared__ int    comp[4][4][K_EP];              // per-wave compacted endpoint ids

    const int s    = blockIdx.x;
    const int tid  = threadIdx.x;
    const int wave = tid >> 6;
    const int lane = tid & 63;

    // ---- runtime detection of bool-mask storage: int32 / uint8 / float32 ----
    const unsigned int* mw = (const unsigned int*)emask;
    unsigned int probe = mw[lane];
    const bool floatMask = (__ballot(probe == 0x3F800000u) != 0ULL);
    const bool byteMask  = !floatMask && (__ballot(probe > 1u) != 0ULL);

    // ---- one coalesced 64-lane load covers ids+mask for this wave's 4 paths ----
    const int base = (s * P_PATHS + wave * 4) * K_EP;
    const int idv  = eids[base + lane];
    int mk;
    if (floatMask)     mk = (((const float*)emask)[base + lane] != 0.0f);
    else if (byteMask) mk = ((const unsigned char*)emask)[base + lane];
    else               mk = ((const int*)emask)[base + lane];
    const unsigned long long bits_all = __ballot(mk != 0);

    const int k16  = lane & 15;
    const int pgrp = lane >> 4;
    const unsigned int bits_p = (unsigned int)((bits_all >> (16 * pgrp)) & 0xFFFFu);

    // compact valid ids; pad slots point at the zero row (bf16 path) so loads need no guards
    comp[wave][pgrp][k16] = USE_BF16 ? nent : 0;
    if (mk) comp[wave][pgrp][__popc(bits_p & ((1u << k16) - 1u))] = idv;
    if (lane < 4) cnts[wave * 4 + lane] = __popc((unsigned int)((bits_all >> (16 * lane)) & 0xFFFFu));

    const int c0 = __popc((unsigned int)( bits_all        & 0xFFFFu));
    const int c1 = __popc((unsigned int)((bits_all >> 16) & 0xFFFFu));
    const int c2 = __popc((unsigned int)((bits_all >> 32) & 0xFFFFu));
    const int c3 = __popc((unsigned int)((bits_all >> 48) & 0xFFFFu));

    const int q   = lane >> 4;       // quarter: owns slots q, q+4, q+8, q+12
    const int c16 = lane & 15;

    if constexpr (USE_BF16) {
        // ---- bf16 gather: quarter-wave per row, 4 paths in parallel, UNCONDITIONAL loads
        // (pad slots hit the zero row: one L1-hot line, adds 0.0). 2-stage register
        // pipeline keeps 8 loads in flight. No per-thread arrays -> spill-proof.
        const uint4* __restrict__ entb = (const uint4*)entbf + c16;
        float4 l0 = {0,0,0,0}, h0 = l0, l1 = l0, h1 = l0, l2 = l0, h2 = l0, l3 = l0, h3 = l0;

        uint4 r0 = entb[(size_t)comp[wave][0][q] * 16];
        uint4 r1 = entb[(size_t)comp[wave][1][q] * 16];
        uint4 r2 = entb[(size_t)comp[wave][2][q] * 16];
        uint4 r3 = entb[(size_t)comp[wave][3][q] * 16];
        #pragma unroll
        for (int u = 0; u < 4; ++u) {
            uint4 n0, n1, n2, n3;
            if (u < 3) {
                const int slot = q + 4 * (u + 1);
                n0 = entb[(size_t)comp[wave][0][slot] * 16];
                n1 = entb[(size_t)comp[wave][1][slot] * 16];
                n2 = entb[(size_t)comp[wave][2][slot] * 16];
                n3 = entb[(size_t)comp[wave][3][slot] * 16];
            }
            acc_row(l0, h0, r0);
            acc_row(l1, h1, r1);
            acc_row(l2, h2, r2);
            acc_row(l3, h3, r3);
            if (u < 3) { r0 = n0; r1 = n1; r2 = n2; r3 = n3; }
        }
        // merge the 4 quarters (xor 16 then 32) -> every lane holds full sums
        merge_xor(l0); merge_xor(h0); merge_xor(l1); merge_xor(h1);
        merge_xor(l2); merge_xor(h2); merge_xor(l3); merge_xor(h3);

        // quarter q stores path q (all 64 lanes active)
        const int   cq   = (q == 0) ? c0 : (q == 1) ? c1 : (q == 2) ? c2 : c3;
        const float invq = 1.0f / (float)(cq > 1 ? cq : 1);
        float4 lo = (q == 0) ? l0 : (q == 1) ? l1 : (q == 2) ? l2 : l3;
        float4 hi = (q == 0) ? h0 : (q == 1) ? h1 : (q == 2) ? h2 : h3;
        lo.x *= invq; lo.y *= invq; lo.z *= invq; lo.w *= invq;
        hi.x *= invq; hi.y *= invq; hi.z *= invq; hi.w *= invq;
        const int pw = wave * 4 + q;
        *(float4*)&aggf[pw][c16 * 8]     = lo;
        *(float4*)&aggf[pw][c16 * 8 + 4] = hi;
        union { __bf16 h[8]; uint4 u4; } pk;
        pk.h[0] = (__bf16)lo.x; pk.h[1] = (__bf16)lo.y; pk.h[2] = (__bf16)lo.z; pk.h[3] = (__bf16)lo.w;
        pk.h[4] = (__bf16)hi.x; pk.h[5] = (__bf16)hi.y; pk.h[6] = (__bf16)hi.z; pk.h[7] = (__bf16)hi.w;
        *(uint4*)&aggbf[pw][c16 * 8] = pk.u4;
    } else {
        // ---- fp32 fallback (round-4 structure, known spill-free) ----
        const int half = lane >> 5;
        const int col  = lane & 31;
        const float4* __restrict__ entc = (const float4*)ent + col;
        float4 acc0 = {0.f,0.f,0.f,0.f}, acc1 = acc0, acc2 = acc0, acc3 = acc0;
        #pragma unroll
        for (int u = 0; u < 8; ++u) {
            const int slot = 2 * u + half;
            const int id0 = comp[wave][0][slot];
            const int id1 = comp[wave][1][slot];
            const int id2 = comp[wave][2][slot];
            const int id3 = comp[wave][3][slot];
            if (slot < c0) { float4 v = entc[(size_t)id0 << 5]; acc0.x += v.x; acc0.y += v.y; acc0.z += v.z; acc0.w += v.w; }
            if (slot < c1) { float4 v = entc[(size_t)id1 << 5]; acc1.x += v.x; acc1.y += v.y; acc1.z += v.z; acc1.w += v.w; }
            if (slot < c2) { float4 v = entc[(size_t)id2 << 5]; acc2.x += v.x; acc2.y += v.y; acc2.z += v.z; acc2.w += v.w; }
            if (slot < c3) { float4 v = entc[(size_t)id3 << 5]; acc3.x += v.x; acc3.y += v.y; acc3.z += v.z; acc3.w += v.w; }
        }
        #pragma unroll
        for (int i = 0; i < 4; ++i) {
            float4 a = (i == 0) ? acc0 : (i == 1) ? acc1 : (i == 2) ? acc2 : acc3;
            const int cnt = (i == 0) ? c0 : (i == 1) ? c1 : (i == 2) ? c2 : c3;
            a.x += __shfl_xor(a.x, 32); a.y += __shfl_xor(a.y, 32);
            a.z += __shfl_xor(a.z, 32); a.w += __shfl_xor(a.w, 32);
            const float inv = 1.0f / (float)(cnt > 1 ? cnt : 1);
            a.x *= inv; a.y *= inv; a.z *= inv; a.w *= inv;
            if (half == 0) {
                const int p = wave * 4 + i;
                *(float4*)&aggf[p][col * 4] = a;
                union { __bf16 h[4]; uint2 u2; } pk;
                pk.h[0] = (__bf16)a.x; pk.h[1] = (__bf16)a.y;
                pk.h[2] = (__bf16)a.z; pk.h[3] = (__bf16)a.w;
                *(uint2*)&aggbf[p][col * 4] = pk.u2;
            }
        }
    }
    __syncthreads();

    if (wave != 0) return;

    // ---- MLP for all 16 paths via MFMA (wave 0) ----
    const int m    = lane & 15;
    const int quad = lane >> 4;

    bf16x8_t afr[4];
    #pragma unroll
    for (int st = 0; st < 4; ++st)
        afr[st] = *(const bf16x8_t*)&aggbf[m][st * 32 + quad * 8];

    float xp[4] = {0.f, 0.f, 0.f, 0.f};
    #pragma unroll
    for (int t = 0; t < 4; ++t) {
        const int n = t * 16 + m;
        const float b1v = b1[n];
        f32x4_t acc = {b1v, b1v, b1v, b1v};
        const __bf16* bp = w1t + n * D_DIM + quad * 8;
        #pragma unroll
        for (int st = 0; st < 4; ++st) {
            bf16x8_t bfr = *(const bf16x8_t*)(bp + st * 32);
            acc = __builtin_amdgcn_mfma_f32_16x16x32_bf16(afr[st], bfr, acc, 0, 0, 0);
        }
        const float w2v = W2[n];
        #pragma unroll
        for (int r = 0; r < 4; ++r) {
            float h = acc[r] > 0.f ? acc[r] : 0.f;
            xp[r] += h * w2v;
        }
    }
    #pragma unroll
    for (int off = 1; off < 16; off <<= 1) {
        #pragma unroll
        for (int r = 0; r < 4; ++r) xp[r] += __shfl_xor(xp[r], off);
    }

    int myc[4]; int localv = 0;
    #pragma unroll
    for (int r = 0; r < 4; ++r) { myc[r] = cnts[quad * 4 + r]; localv += (myc[r] > 0); }
    int nv = localv + __shfl_xor(localv, 16);
    nv += __shfl_xor(nv, 32);
    const float invnv = 1.0f / (float)(nv > 1 ? nv : 1);
    const float b2v = b2[0];

    float wv[4];
    #pragma unroll
    for (int r = 0; r < 4; ++r) {
        float x = xp[r] + b2v;
        float w = 1.0f / (1.0f + __expf(-x));
        wv[r] = (myc[r] > 0) ? w * invnv : 0.f;
    }

    float fx = 0.f, fy = 0.f;
    #pragma unroll
    for (int p = 0; p < P_PATHS; ++p) {
        float wp = __shfl(wv[p & 3], (p >> 2) << 4);
        float2 a = *(const float2*)&aggf[p][2 * lane];
        fx += wp * a.x; fy += wp * a.y;
    }
    const int row = sids[s];
    *(float2*)&out[(size_t)row * D_DIM + 2 * lane] = make_float2(fx, fy);
}

extern "C" void kernel_launch(void* const* d_in, const int* in_sizes, int n_in,
                              void* d_out, int out_size, void* d_ws, size_t ws_size,
                              hipStream_t stream)
{
    const float* ent  = (const float*)d_in[0];
    const float* W1   = (const float*)d_in[1];
    const float* b1   = (const float*)d_in[2];
    const float* W2   = (const float*)d_in[3];
    const float* b2   = (const float*)d_in[4];
    const int*   sids = (const int*)d_in[5];
    const int*   eids = (const int*)d_in[6];
    const void*  emsk = (const void*)d_in[7];
    float* out = (float*)d_out;

    const int ND   = in_sizes[0];                     // N*D elements of entity table
    const int nent = ND / D_DIM;                      // N (pad row index)
    __bf16* w1t_ws = (__bf16*)d_ws;                   // 16 KB
    __bf16* entbf  = (__bf16*)((char*)d_ws + 16384);  // 2*(ND + D) bytes (incl. pad row)
    const bool useBf16 = (ws_size >= 16384 + ((size_t)ND + D_DIM) * 2)
                         && ((ND & 3) == 0) && ((out_size & 3) == 0);

    if (useBf16) {
        const int n4 = ND >> 2, o4 = out_size >> 2;
        const int mx = n4 > o4 ? n4 : o4;
        prep_fused_kernel<<<(mx + 255) / 256, 256, 0, stream>>>(ent, W1, entbf, w1t_ws,
                                                                (float4*)out, n4, o4);
        PathGuidedAggregator_kernel<true><<<S_NODES, 256, 0, stream>>>(
            ent, (const __bf16*)entbf, b1, W2, b2, sids, eids, emsk,
            (const __bf16*)w1t_ws, out, nent);
    } else {
        hipMemsetAsync(d_out, 0, (size_t)out_size * sizeof(float), stream);
        prep_w1_kernel<<<32, 256, 0, stream>>>(W1, w1t_ws);
        PathGuidedAggregator_kernel<false><<<S_NODES, 256, 0, stream>>>(
            ent, (const __bf16*)entbf, b1, W2, b2, sids, eids, emsk,
            (const __bf16*)w1t_ws, out, nent);
    }
}